// Round 14
// baseline (2394.232 us; speedup 1.0000x reference)
//
#include <hip/hip_runtime.h>
#include <hip/hip_bf16.h>

#define TT 20
#define NN 50000
#define EE 800000
#define IND 16
#define HH 128
#define NPF 7
#define CC 4                    // fixed chunk of timesteps (20 % 4 == 0)
#define NB ((NN + 255) / 256)   // 196 scan blocks

typedef __attribute__((ext_vector_type(8))) short bf16x8;
typedef __attribute__((ext_vector_type(4))) float f32x4;
#define MFMA(a, b, c) __builtin_amdgcn_mfma_f32_16x16x32_bf16(a, b, c, 0, 0, 0)

__device__ __forceinline__ unsigned short f2bf(float f) {
    union { float f; unsigned u; } v; v.f = f;
    unsigned r = v.u + 0x7fffu + ((v.u >> 16) & 1u);
    return (unsigned short)(r >> 16);
}
__device__ __forceinline__ float bf2f(unsigned short u) {
    union { unsigned u; float f; } v; v.u = ((unsigned)u) << 16;
    return v.f;
}

// ---------------------------------------------------------------------------
// Edge-dtype detection (int64 vs int32) + CSR build.
__global__ void detect_kernel(const int* ei, int* flag, int E) {
    __shared__ int nz;
    if (threadIdx.x == 0) nz = 0;
    __syncthreads();
    for (int i = threadIdx.x; i < 1024 && i < E; i += blockDim.x)
        if (ei[2 * i + 1] != 0) atomicOr(&nz, 1);
    __syncthreads();
    if (threadIdx.x == 0) *flag = (nz == 0) ? 1 : 0;
}
__device__ __forceinline__ int edge_src(const int* ei, int e, int E, int f) {
    return f ? ei[2 * e] : ei[e];
}
__device__ __forceinline__ int edge_dst(const int* ei, int e, int E, int f) {
    return f ? ei[2 * (E + e)] : ei[E + e];
}
__global__ void count_deg_kernel(const int* ei, const int* flag, int* deg, int E) {
    int e = blockIdx.x * blockDim.x + threadIdx.x;
    if (e >= E) return;
    int f = *flag;
    atomicAdd(&deg[edge_dst(ei, e, E, f)], 1);
}

// Parallel scan, 3 stages.
__global__ __launch_bounds__(256) void sum_blocks_kernel(const int* deg, int* bsum) {
    int i = blockIdx.x * 256 + threadIdx.x;
    int v = (i < NN) ? deg[i] : 0;
#pragma unroll
    for (int o = 1; o <= 32; o <<= 1) v += __shfl_xor(v, o);
    __shared__ int ws[4];
    if ((threadIdx.x & 63) == 0) ws[threadIdx.x >> 6] = v;
    __syncthreads();
    if (threadIdx.x == 0) bsum[blockIdx.x] = ws[0] + ws[1] + ws[2] + ws[3];
}
__global__ __launch_bounds__(256) void scan_blocks_kernel(const int* bsum, int* bbase) {
    __shared__ int arr[256];
    int t = threadIdx.x;
    int v = (t < NB) ? bsum[t] : 0;
    arr[t] = v;
    __syncthreads();
    for (int off = 1; off < 256; off <<= 1) {
        int u = (t >= off) ? arr[t - off] : 0;
        __syncthreads();
        arr[t] += u;
        __syncthreads();
    }
    if (t < NB) bbase[t] = arr[t] - v;
}
__global__ __launch_bounds__(256) void offs_kernel(const int* deg, const int* bbase,
                                                   int* offs, int* cursor,
                                                   float* dinv, int E) {
    __shared__ int arr[256];
    int t = threadIdx.x;
    int i = blockIdx.x * 256 + t;
    int d = (i < NN) ? deg[i] : 0;
    arr[t] = d;
    __syncthreads();
    for (int off = 1; off < 256; off <<= 1) {
        int u = (t >= off) ? arr[t - off] : 0;
        __syncthreads();
        arr[t] += u;
        __syncthreads();
    }
    if (i < NN) {
        int o = bbase[blockIdx.x] + arr[t] - d;
        offs[i] = o;
        cursor[i] = o;
        dinv[i] = 1.0f / (float)(d > 1 ? d : 1);
        if (i == NN - 1) offs[NN] = E;
    }
}
__global__ void fill_csr_kernel(const int* ei, const int* flag, int* cursor,
                                int* csr, int E) {
    int e = blockIdx.x * blockDim.x + threadIdx.x;
    if (e >= E) return;
    int f = *flag;
    int s = edge_src(ei, e, E, f);
    int d = edge_dst(ei, e, E, f);
    int p = atomicAdd(&cursor[d], 1);
    csr[p] = s;
}

// ---------------------------------------------------------------------------
// Pack ALL six weight matrices into MFMA B-fragment order in one launch.
__global__ void pack_all_kernel(
    const float* s2wl, const float* s2wr, const float* tw1, const float* pw1,
    const float* wih, const float* whh,
    unsigned short* pS2L, unsigned short* pS2R, unsigned short* pT1,
    unsigned short* pP1, unsigned short* pGI, unsigned short* pGH) {
    int id = blockIdx.x * blockDim.x + threadIdx.x;
    if (id >= 80 * 256) return;
    int gt = id >> 8;            // global tile index
    int lane = id & 63, kk = (id >> 6) & 3;
    const float* src; unsigned short* dst; int tile, mode, ncols;
    if (gt < 8)       { src = s2wl; dst = pS2L; tile = gt;      mode = 0; ncols = 128; }
    else if (gt < 16) { src = s2wr; dst = pS2R; tile = gt - 8;  mode = 0; ncols = 128; }
    else if (gt < 24) { src = tw1;  dst = pT1;  tile = gt - 16; mode = 0; ncols = 128; }
    else if (gt < 32) { src = pw1;  dst = pP1;  tile = gt - 24; mode = 0; ncols = 128; }
    else if (gt < 56) { src = wih;  dst = pGI;  tile = gt - 32; mode = 1; ncols = 384; }
    else              { src = whh;  dst = pGH;  tile = gt - 56; mode = 1; ncols = 384; }
    int n = tile * 16 + (lane & 15);
    int kbase = kk * 32 + (lane >> 4) * 8;
    unsigned short out[8];
#pragma unroll
    for (int i = 0; i < 8; ++i) {
        int k = kbase + i;
        float v = mode ? src[n * HH + k] : src[k * ncols + n];
        out[i] = f2bf(v);
    }
    *(uint4*)(dst + ((size_t)tile * 256 + kk * 64 + lane) * 8) = *(uint4*)out;
}

// ---------------------------------------------------------------------------
// SAGE-1 (gather + GEMM fused), grid (NN/8, CC). h1 TIME-INTERLEAVED:
// h1c[n][ci][col] bf16 -> each node's CC timesteps are one 1KB block.
__global__ __launch_bounds__(128) void sage1_kernel(
    const float* __restrict__ x, const int* __restrict__ offs,
    const int* __restrict__ csr, const float* __restrict__ dinv,
    const float* __restrict__ wl, const float* __restrict__ bl,
    const float* __restrict__ wr, unsigned short* __restrict__ h1c, int t0) {
    const int tid = threadIdx.x;
    const int ci = blockIdx.y;
    const float* xt = x + (size_t)(t0 + ci) * NN * IND;
    const int m0 = blockIdx.x * 8;
    __shared__ __align__(16) float sAgg[8][IND];
    __shared__ float sX[8][IND];
    {
        int r = tid >> 4, node = m0 + r;
        int l16 = tid & 15, sub = l16 >> 2, q = l16 & 3;
        int e1 = offs[node + 1];
        float4 a0 = make_float4(0.f, 0.f, 0.f, 0.f);
        float4 a1 = make_float4(0.f, 0.f, 0.f, 0.f);
        float4 a2 = make_float4(0.f, 0.f, 0.f, 0.f);
        float4 a3 = make_float4(0.f, 0.f, 0.f, 0.f);
        int e = offs[node] + sub;
        for (; e + 12 < e1; e += 16) {
            int s0 = __builtin_nontemporal_load(&csr[e]);
            int s1 = __builtin_nontemporal_load(&csr[e + 4]);
            int s2 = __builtin_nontemporal_load(&csr[e + 8]);
            int s3 = __builtin_nontemporal_load(&csr[e + 12]);
            float4 v0 = *(const float4*)(xt + (size_t)s0 * IND + q * 4);
            float4 v1 = *(const float4*)(xt + (size_t)s1 * IND + q * 4);
            float4 v2 = *(const float4*)(xt + (size_t)s2 * IND + q * 4);
            float4 v3 = *(const float4*)(xt + (size_t)s3 * IND + q * 4);
            a0.x += v0.x; a0.y += v0.y; a0.z += v0.z; a0.w += v0.w;
            a1.x += v1.x; a1.y += v1.y; a1.z += v1.z; a1.w += v1.w;
            a2.x += v2.x; a2.y += v2.y; a2.z += v2.z; a2.w += v2.w;
            a3.x += v3.x; a3.y += v3.y; a3.z += v3.z; a3.w += v3.w;
        }
        for (; e < e1; e += 4) {
            int s0 = __builtin_nontemporal_load(&csr[e]);
            float4 v0 = *(const float4*)(xt + (size_t)s0 * IND + q * 4);
            a0.x += v0.x; a0.y += v0.y; a0.z += v0.z; a0.w += v0.w;
        }
        float4 acc;
        acc.x = a0.x + a1.x + a2.x + a3.x;
        acc.y = a0.y + a1.y + a2.y + a3.y;
        acc.z = a0.z + a1.z + a2.z + a3.z;
        acc.w = a0.w + a1.w + a2.w + a3.w;
#pragma unroll
        for (int o = 4; o <= 8; o <<= 1) {
            acc.x += __shfl_xor(acc.x, o);
            acc.y += __shfl_xor(acc.y, o);
            acc.z += __shfl_xor(acc.z, o);
            acc.w += __shfl_xor(acc.w, o);
        }
        if (sub == 0) {
            float di = dinv[node];
            acc.x *= di; acc.y *= di; acc.z *= di; acc.w *= di;
            *(float4*)&sAgg[r][q * 4] = acc;
        }
        sX[r][l16] = xt[(size_t)node * IND + l16];
    }
    __syncthreads();
    const int col = tid;
    float acc[8];
    float b = bl[col];
#pragma unroll
    for (int m = 0; m < 8; ++m) acc[m] = b;
#pragma unroll
    for (int k = 0; k < IND; ++k) {
        float wlv = wl[k * HH + col];
        float wrv = wr[k * HH + col];
#pragma unroll
        for (int m = 0; m < 8; ++m) acc[m] += sAgg[m][k] * wlv + sX[m][k] * wrv;
    }
#pragma unroll
    for (int m = 0; m < 8; ++m)
        h1c[((size_t)(m0 + m) * CC + ci) * HH + col] = f2bf(fmaxf(acc[m], 0.f));
}

// SAGE-2 aggregation over interleaved h1 (R7 4-deep form — best measured).
#define ADD8(acc, v) do {                                     \
    union { unsigned u; float f; } t_;                        \
    t_.u = (v).x << 16;         acc[0] += t_.f;               \
    t_.u = (v).x & 0xffff0000u; acc[1] += t_.f;               \
    t_.u = (v).y << 16;         acc[2] += t_.f;               \
    t_.u = (v).y & 0xffff0000u; acc[3] += t_.f;               \
    t_.u = (v).z << 16;         acc[4] += t_.f;               \
    t_.u = (v).z & 0xffff0000u; acc[5] += t_.f;               \
    t_.u = (v).w << 16;         acc[6] += t_.f;               \
    t_.u = (v).w & 0xffff0000u; acc[7] += t_.f;               \
} while (0)

__global__ __launch_bounds__(256) void sage2_agg_kernel(
    const unsigned short* __restrict__ h1c, const int* __restrict__ offs,
    const int* __restrict__ csr, const float* __restrict__ dinv,
    unsigned short* __restrict__ agg2c) {
    const int wid = threadIdx.x >> 6, lane = threadIdx.x & 63;
    const int n = blockIdx.x * 4 + wid;
    const char* __restrict__ tb = (const char*)h1c;
    const int lb = lane * 16;
    const int e0 = offs[n], e1 = offs[n + 1];
    float a[8] = {0,0,0,0,0,0,0,0}, b[8] = {0,0,0,0,0,0,0,0};
    float c_[8] = {0,0,0,0,0,0,0,0}, d[8] = {0,0,0,0,0,0,0,0};
    int e = e0;
    for (; e + 3 < e1; e += 4) {
        int s0 = csr[e], s1 = csr[e + 1], s2 = csr[e + 2], s3 = csr[e + 3];
        uint4 v0 = *(const uint4*)(tb + (size_t)s0 * 1024 + lb);
        uint4 v1 = *(const uint4*)(tb + (size_t)s1 * 1024 + lb);
        uint4 v2 = *(const uint4*)(tb + (size_t)s2 * 1024 + lb);
        uint4 v3 = *(const uint4*)(tb + (size_t)s3 * 1024 + lb);
        ADD8(a, v0); ADD8(b, v1); ADD8(c_, v2); ADD8(d, v3);
    }
    for (; e < e1; ++e) {
        int s0 = csr[e];
        uint4 v0 = *(const uint4*)(tb + (size_t)s0 * 1024 + lb);
        ADD8(a, v0);
    }
    float di = dinv[n];
    unsigned short o[8];
#pragma unroll
    for (int j = 0; j < 8; ++j) o[j] = f2bf((a[j] + b[j] + c_[j] + d[j]) * di);
    *(uint4*)((char*)agg2c + (size_t)n * 1024 + lb) = *(uint4*)o;
}

// ---------------------------------------------------------------------------
// A-frag read from XOR-swizzled bf16 LDS tile (16 rows x 128 cols).
#define LDA(buf, kk)                                                          \
    (*(const bf16x8*)((const char*)(buf) +                                    \
        (((lane & 15) * 256 + (kk) * 64 + (lane >> 4) * 16) ^                 \
         (((lane & 15) & 7) << 4))))

// Fused per-slice kernel: sage2-GEMM + LN + GRU + BOTH DECODERS, straight-
// line (no timestep loop -> no cross-iteration hoisting / spill; proven in
// R2). 1 wave, 16 nodes. 2 LDS buffers (8KB); h_new bf16 reuses bufB.
// __launch_bounds__(64,4) caps VGPR at 128 -> 16 waves/CU eligible.
__global__ __launch_bounds__(64, 4) void gru_dec_kernel(
    const unsigned short* __restrict__ agg2c, const unsigned short* __restrict__ h1c,
    const unsigned short* __restrict__ pS2L, const unsigned short* __restrict__ pS2R,
    const float* __restrict__ s2bl, const float* __restrict__ lng,
    const float* __restrict__ lnb,
    const unsigned short* __restrict__ pGI, const unsigned short* __restrict__ pGH,
    const float* __restrict__ bih, const float* __restrict__ bhh,
    float* __restrict__ h,
    const unsigned short* __restrict__ pT1, const unsigned short* __restrict__ pP1,
    const float* __restrict__ tb1, const float* __restrict__ tw2,
    const float* __restrict__ tb2, const float* __restrict__ pb1,
    const float* __restrict__ pw2, const float* __restrict__ pb2,
    float* __restrict__ out_th, float* __restrict__ out_ph, int ci) {
    const int lane = threadIdx.x;
    const int r0 = blockIdx.x * 16;
    __shared__ unsigned short bufA[16 * 128];  // agg2 -> enc
    __shared__ unsigned short bufB[16 * 128];  // h1 -> h_old bf16 -> h_new bf16

#pragma unroll
    for (int j = 0; j < 4; ++j) {
        int off = (lane + 64 * j) * 16;
        int row = off >> 8, colb = off & 255;
        int swz = off ^ ((row & 7) << 4);
        size_t src = (size_t)(r0 + row) * 1024 + (size_t)ci * 256 + colb;
        *(uint4*)((char*)bufA + swz) = *(const uint4*)((const char*)agg2c + src);
        *(uint4*)((char*)bufB + swz) = *(const uint4*)((const char*)h1c + src);
    }
    __syncthreads();

    // register the phase-1 fragments before bufB is recycled
    bf16x8 ae[4], ah[4];
#pragma unroll
    for (int kk = 0; kk < 4; ++kk) { ae[kk] = LDA(bufA, kk); ah[kk] = LDA(bufB, kk); }
    __syncthreads();

    // bufB <- h_old bf16 (loads overlap phase-1 compute below)
#pragma unroll
    for (int j = 0; j < 4; ++j) {
        int off = (lane + 64 * j) * 16;
        int row = off >> 8;
        int swz = off ^ ((row & 7) << 4);
        const float* hs = h + (size_t)r0 * HH + (size_t)(off / 2);
        unsigned short tmp[8];
#pragma unroll
        for (int i = 0; i < 8; ++i) tmp[i] = f2bf(hs[i]);
        *(uint4*)((char*)bufB + swz) = *(uint4*)tmp;
    }

    // ---- phase 1: enc = LN(relu(agg2@wl + bl + h1@wr))
    float vE[8][4];
    float sS[4] = {0, 0, 0, 0}, sQ[4] = {0, 0, 0, 0};
#pragma unroll
    for (int c = 0; c < 8; ++c) {
        f32x4 al = {0, 0, 0, 0}, ar = {0, 0, 0, 0};
#pragma unroll
        for (int kk = 0; kk < 4; ++kk) {
            bf16x8 bl = *(const bf16x8*)(pS2L + ((size_t)(c * 4 + kk) * 64 + lane) * 8);
            bf16x8 br = *(const bf16x8*)(pS2R + ((size_t)(c * 4 + kk) * 64 + lane) * 8);
            al = MFMA(ae[kk], bl, al);
            ar = MFMA(ah[kk], br, ar);
        }
        int col = c * 16 + (lane & 15);
        float bb = s2bl[col];
#pragma unroll
        for (int j = 0; j < 4; ++j) {
            float v = fmaxf(al[j] + ar[j] + bb, 0.f);
            vE[c][j] = v; sS[j] += v; sQ[j] += v * v;
        }
    }
#pragma unroll
    for (int o = 1; o <= 8; o <<= 1) {
#pragma unroll
        for (int j = 0; j < 4; ++j) {
            sS[j] += __shfl_xor(sS[j], o);
            sQ[j] += __shfl_xor(sQ[j], o);
        }
    }
    __syncthreads();
#pragma unroll
    for (int c = 0; c < 8; ++c) {
        int col = c * 16 + (lane & 15);
        float g = lng[col], b = lnb[col];
#pragma unroll
        for (int j = 0; j < 4; ++j) {
            float mu = sS[j] * (1.f / 128.f);
            float var = sQ[j] * (1.f / 128.f) - mu * mu;
            float ve = (vE[c][j] - mu) * rsqrtf(var + 1e-5f) * g + b;
            int row = (lane >> 4) * 4 + j;
            int off = ((row * 128 + col) * 2) ^ ((row & 7) << 4);
            *(unsigned short*)((char*)bufA + off) = f2bf(ve);
        }
    }
    __syncthreads();

    // ---- phase 2: GRU; h -> global fp32, h_new bf16 -> bufB (reuse)
    bf16x8 xe[4], xh[4];
#pragma unroll
    for (int kk = 0; kk < 4; ++kk) { xe[kk] = LDA(bufA, kk); xh[kk] = LDA(bufB, kk); }
#pragma unroll
    for (int c = 0; c < 8; ++c) {
        f32x4 air = {0,0,0,0}, aiz = {0,0,0,0}, ain = {0,0,0,0};
        f32x4 ahr = {0,0,0,0}, ahz = {0,0,0,0}, ahn = {0,0,0,0};
#pragma unroll
        for (int kk = 0; kk < 4; ++kk) {
            bf16x8 bir = *(const bf16x8*)(pGI + ((size_t)((c     ) * 4 + kk) * 64 + lane) * 8);
            bf16x8 biz = *(const bf16x8*)(pGI + ((size_t)((c +  8) * 4 + kk) * 64 + lane) * 8);
            bf16x8 bin = *(const bf16x8*)(pGI + ((size_t)((c + 16) * 4 + kk) * 64 + lane) * 8);
            bf16x8 bhr = *(const bf16x8*)(pGH + ((size_t)((c     ) * 4 + kk) * 64 + lane) * 8);
            bf16x8 bhz = *(const bf16x8*)(pGH + ((size_t)((c +  8) * 4 + kk) * 64 + lane) * 8);
            bf16x8 bhn = *(const bf16x8*)(pGH + ((size_t)((c + 16) * 4 + kk) * 64 + lane) * 8);
            air = MFMA(xe[kk], bir, air); aiz = MFMA(xe[kk], biz, aiz);
            ain = MFMA(xe[kk], bin, ain);
            ahr = MFMA(xh[kk], bhr, ahr); ahz = MFMA(xh[kk], bhz, ahz);
            ahn = MFMA(xh[kk], bhn, ahn);
        }
        int col = c * 16 + (lane & 15);
        float bir_ = bih[col], biz_ = bih[HH + col], bin_ = bih[2 * HH + col];
        float bhr_ = bhh[col], bhz_ = bhh[HH + col], bhn_ = bhh[2 * HH + col];
#pragma unroll
        for (int j = 0; j < 4; ++j) {
            int row = (lane >> 4) * 4 + j;
            size_t gidx = (size_t)(r0 + row) * HH + col;
            float rr = 1.f / (1.f + expf(-(air[j] + bir_ + ahr[j] + bhr_)));
            float zz = 1.f / (1.f + expf(-(aiz[j] + biz_ + ahz[j] + bhz_)));
            float nn2 = tanhf(ain[j] + bin_ + rr * (ahn[j] + bhn_));
            float hold = h[gidx];
            float hnew = (1.f - zz) * nn2 + zz * hold;
            h[gidx] = hnew;
            int off = ((row * 128 + col) * 2) ^ ((row & 7) << 4);
            *(unsigned short*)((char*)bufB + off) = f2bf(hnew);
        }
    }
    __syncthreads();

    // ---- phase 3: decoders on h_new (bufB)
    bf16x8 xd[4];
#pragma unroll
    for (int kk = 0; kk < 4; ++kk) xd[kk] = LDA(bufB, kk);
    float pt[4] = {0, 0, 0, 0};
    float pf[NPF][4];
#pragma unroll
    for (int f = 0; f < NPF; ++f)
#pragma unroll
        for (int j = 0; j < 4; ++j) pf[f][j] = 0.f;
#pragma unroll
    for (int c = 0; c < 8; ++c) {
        f32x4 at = {0, 0, 0, 0}, ap = {0, 0, 0, 0};
#pragma unroll
        for (int kk = 0; kk < 4; ++kk) {
            bf16x8 bt = *(const bf16x8*)(pT1 + ((size_t)(c * 4 + kk) * 64 + lane) * 8);
            bf16x8 bp = *(const bf16x8*)(pP1 + ((size_t)(c * 4 + kk) * 64 + lane) * 8);
            at = MFMA(xd[kk], bt, at);
            ap = MFMA(xd[kk], bp, ap);
        }
        int col = c * 16 + (lane & 15);
        float b1 = tb1[col], b2 = pb1[col], w2 = tw2[col];
        float wp[NPF];
#pragma unroll
        for (int f = 0; f < NPF; ++f) wp[f] = pw2[col * NPF + f];
#pragma unroll
        for (int j = 0; j < 4; ++j) {
            float a = fmaxf(at[j] + b1, 0.f);
            pt[j] += a * w2;
            float p = fmaxf(ap[j] + b2, 0.f);
#pragma unroll
            for (int f = 0; f < NPF; ++f) pf[f][j] += p * wp[f];
        }
    }
#pragma unroll
    for (int o = 1; o <= 8; o <<= 1) {
#pragma unroll
        for (int j = 0; j < 4; ++j) {
            pt[j] += __shfl_xor(pt[j], o);
#pragma unroll
            for (int f = 0; f < NPF; ++f) pf[f][j] += __shfl_xor(pf[f][j], o);
        }
    }
    if ((lane & 15) == 0) {
        int g = lane >> 4;
#pragma unroll
        for (int j = 0; j < 4; ++j) {
            int gr = r0 + g * 4 + j;
            out_th[gr] = pt[j] + tb2[0];
#pragma unroll
            for (int f = 0; f < NPF; ++f)
                out_ph[(size_t)gr * NPF + f] = pf[f][j] + pb2[f];
        }
    }
}
#undef LDA

// ---------------------------------------------------------------------------
extern "C" void kernel_launch(void* const* d_in, const int* in_sizes, int n_in,
                              void* d_out, int out_size, void* d_ws, size_t ws_size,
                              hipStream_t stream) {
    const float* x     = (const float*)d_in[0];
    const int*   ei    = (const int*)d_in[1];
    const float* s1wl  = (const float*)d_in[2];
    const float* s1bl  = (const float*)d_in[3];
    const float* s1wr  = (const float*)d_in[4];
    const float* s2wl  = (const float*)d_in[5];
    const float* s2bl  = (const float*)d_in[6];
    const float* s2wr  = (const float*)d_in[7];
    const float* lng   = (const float*)d_in[8];
    const float* lnb   = (const float*)d_in[9];
    const float* g_wih = (const float*)d_in[10];
    const float* g_whh = (const float*)d_in[11];
    const float* g_bih = (const float*)d_in[12];
    const float* g_bhh = (const float*)d_in[13];
    const float* tw1   = (const float*)d_in[14];
    const float* tb1   = (const float*)d_in[15];
    const float* tw2   = (const float*)d_in[16];
    const float* tb2   = (const float*)d_in[17];
    const float* pw1   = (const float*)d_in[18];
    const float* pb1   = (const float*)d_in[19];
    const float* pw2   = (const float*)d_in[20];
    const float* pb2   = (const float*)d_in[21];

    char* ws = (char*)d_ws;
    size_t o = 0;
    auto alloc = [&](size_t bytes) {
        size_t r = o;
        o += (bytes + 255) & ~(size_t)255;
        return r;
    };
    int*            flag  = (int*)(ws + alloc(4));
    int*            deg   = (int*)(ws + alloc((size_t)NN * 4));
    int*            offs  = (int*)(ws + alloc((size_t)(NN + 1) * 4));
    int*            curs  = (int*)(ws + alloc((size_t)NN * 4));
    int*            csr   = (int*)(ws + alloc((size_t)EE * 4));
    float*          dinv  = (float*)(ws + alloc((size_t)NN * 4));
    int*            bsum  = (int*)(ws + alloc((size_t)NB * 4));
    int*            bbase = (int*)(ws + alloc((size_t)NB * 4));
    unsigned short* pS2L  = (unsigned short*)(ws + alloc(8 * 4 * 64 * 8 * 2));
    unsigned short* pS2R  = (unsigned short*)(ws + alloc(8 * 4 * 64 * 8 * 2));
    unsigned short* pT1   = (unsigned short*)(ws + alloc(8 * 4 * 64 * 8 * 2));
    unsigned short* pP1   = (unsigned short*)(ws + alloc(8 * 4 * 64 * 8 * 2));
    unsigned short* pGI   = (unsigned short*)(ws + alloc(24 * 4 * 64 * 8 * 2));
    unsigned short* pGH   = (unsigned short*)(ws + alloc(24 * 4 * 64 * 8 * 2));
    float*          hbuf  = (float*)(ws + alloc((size_t)NN * HH * 4));
    unsigned short* h1c   = (unsigned short*)(ws + alloc((size_t)NN * CC * HH * 2));
    unsigned short* agg2c = (unsigned short*)(ws + alloc((size_t)NN * CC * HH * 2));

    // Prep (identical every call).
    detect_kernel<<<1, 256, 0, stream>>>(ei, flag, EE);
    hipMemsetAsync(deg, 0, (size_t)NN * 4, stream);
    count_deg_kernel<<<(EE + 255) / 256, 256, 0, stream>>>(ei, flag, deg, EE);
    sum_blocks_kernel<<<NB, 256, 0, stream>>>(deg, bsum);
    scan_blocks_kernel<<<1, 256, 0, stream>>>(bsum, bbase);
    offs_kernel<<<NB, 256, 0, stream>>>(deg, bbase, offs, curs, dinv, EE);
    fill_csr_kernel<<<(EE + 255) / 256, 256, 0, stream>>>(ei, flag, curs, csr, EE);
    pack_all_kernel<<<(80 * 256 + 255) / 256, 256, 0, stream>>>(
        s2wl, s2wr, tw1, pw1, g_wih, g_whh, pS2L, pS2R, pT1, pP1, pGI, pGH);
    hipMemsetAsync(hbuf, 0, (size_t)NN * HH * 4, stream);

    float* out = (float*)d_out;
    for (int t0 = 0; t0 < TT; t0 += CC) {
        dim3 g1(NN / 8, CC);
        sage1_kernel<<<g1, 128, 0, stream>>>(x, offs, csr, dinv, s1wl, s1bl,
                                             s1wr, h1c, t0);
        sage2_agg_kernel<<<NN / 4, 256, 0, stream>>>(h1c, offs, csr, dinv, agg2c);
        for (int ci = 0; ci < CC; ++ci) {
            int tg = t0 + ci;
            gru_dec_kernel<<<NN / 16, 64, 0, stream>>>(
                agg2c, h1c, pS2L, pS2R, s2bl, lng, lnb, pGI, pGH,
                g_bih, g_bhh, hbuf, pT1, pP1, tb1, tw2, tb2, pb1, pw2, pb2,
                out + (size_t)tg * NN,
                out + (size_t)TT * NN + (size_t)tg * NN * NPF, ci);
        }
    }
}

// Round 15
// 2299.197 us; speedup vs baseline: 1.0413x; 1.0413x over previous
//
#include <hip/hip_runtime.h>
#include <hip/hip_bf16.h>

#define TT 20
#define NN 50000
#define EE 800000
#define IND 16
#define HH 128
#define NPF 7
#define CC 4                    // fixed chunk of timesteps (20 % 4 == 0)
#define NB ((NN + 255) / 256)   // 196 scan blocks

typedef __attribute__((ext_vector_type(8))) short bf16x8;
typedef __attribute__((ext_vector_type(4))) float f32x4;
#define MFMA(a, b, c) __builtin_amdgcn_mfma_f32_16x16x32_bf16(a, b, c, 0, 0, 0)

__device__ __forceinline__ unsigned short f2bf(float f) {
    union { float f; unsigned u; } v; v.f = f;
    unsigned r = v.u + 0x7fffu + ((v.u >> 16) & 1u);
    return (unsigned short)(r >> 16);
}
__device__ __forceinline__ float bf2f(unsigned short u) {
    union { unsigned u; float f; } v; v.u = ((unsigned)u) << 16;
    return v.f;
}

// ---------------------------------------------------------------------------
// Edge-dtype detection (int64 vs int32) + CSR build.
__global__ void detect_kernel(const int* ei, int* flag, int E) {
    __shared__ int nz;
    if (threadIdx.x == 0) nz = 0;
    __syncthreads();
    for (int i = threadIdx.x; i < 1024 && i < E; i += blockDim.x)
        if (ei[2 * i + 1] != 0) atomicOr(&nz, 1);
    __syncthreads();
    if (threadIdx.x == 0) *flag = (nz == 0) ? 1 : 0;
}
__device__ __forceinline__ int edge_src(const int* ei, int e, int E, int f) {
    return f ? ei[2 * e] : ei[e];
}
__device__ __forceinline__ int edge_dst(const int* ei, int e, int E, int f) {
    return f ? ei[2 * (E + e)] : ei[E + e];
}
__global__ void count_deg_kernel(const int* ei, const int* flag, int* deg, int E) {
    int e = blockIdx.x * blockDim.x + threadIdx.x;
    if (e >= E) return;
    int f = *flag;
    atomicAdd(&deg[edge_dst(ei, e, E, f)], 1);
}

// Parallel scan, 3 stages.
__global__ __launch_bounds__(256) void sum_blocks_kernel(const int* deg, int* bsum) {
    int i = blockIdx.x * 256 + threadIdx.x;
    int v = (i < NN) ? deg[i] : 0;
#pragma unroll
    for (int o = 1; o <= 32; o <<= 1) v += __shfl_xor(v, o);
    __shared__ int ws[4];
    if ((threadIdx.x & 63) == 0) ws[threadIdx.x >> 6] = v;
    __syncthreads();
    if (threadIdx.x == 0) bsum[blockIdx.x] = ws[0] + ws[1] + ws[2] + ws[3];
}
__global__ __launch_bounds__(256) void scan_blocks_kernel(const int* bsum, int* bbase) {
    __shared__ int arr[256];
    int t = threadIdx.x;
    int v = (t < NB) ? bsum[t] : 0;
    arr[t] = v;
    __syncthreads();
    for (int off = 1; off < 256; off <<= 1) {
        int u = (t >= off) ? arr[t - off] : 0;
        __syncthreads();
        arr[t] += u;
        __syncthreads();
    }
    if (t < NB) bbase[t] = arr[t] - v;
}
__global__ __launch_bounds__(256) void offs_kernel(const int* deg, const int* bbase,
                                                   int* offs, int* cursor,
                                                   float* dinv, int E) {
    __shared__ int arr[256];
    int t = threadIdx.x;
    int i = blockIdx.x * 256 + t;
    int d = (i < NN) ? deg[i] : 0;
    arr[t] = d;
    __syncthreads();
    for (int off = 1; off < 256; off <<= 1) {
        int u = (t >= off) ? arr[t - off] : 0;
        __syncthreads();
        arr[t] += u;
        __syncthreads();
    }
    if (i < NN) {
        int o = bbase[blockIdx.x] + arr[t] - d;
        offs[i] = o;
        cursor[i] = o;
        dinv[i] = 1.0f / (float)(d > 1 ? d : 1);
        if (i == NN - 1) offs[NN] = E;
    }
}
__global__ void fill_csr_kernel(const int* ei, const int* flag, int* cursor,
                                int* csr, int E) {
    int e = blockIdx.x * blockDim.x + threadIdx.x;
    if (e >= E) return;
    int f = *flag;
    int s = edge_src(ei, e, E, f);
    int d = edge_dst(ei, e, E, f);
    int p = atomicAdd(&cursor[d], 1);
    csr[p] = s;
}

// ---------------------------------------------------------------------------
// Pack ALL six weight matrices into MFMA B-fragment order in one launch.
__global__ void pack_all_kernel(
    const float* s2wl, const float* s2wr, const float* tw1, const float* pw1,
    const float* wih, const float* whh,
    unsigned short* pS2L, unsigned short* pS2R, unsigned short* pT1,
    unsigned short* pP1, unsigned short* pGI, unsigned short* pGH) {
    int id = blockIdx.x * blockDim.x + threadIdx.x;
    if (id >= 80 * 256) return;
    int gt = id >> 8;            // global tile index
    int lane = id & 63, kk = (id >> 6) & 3;
    const float* src; unsigned short* dst; int tile, mode, ncols;
    if (gt < 8)       { src = s2wl; dst = pS2L; tile = gt;      mode = 0; ncols = 128; }
    else if (gt < 16) { src = s2wr; dst = pS2R; tile = gt - 8;  mode = 0; ncols = 128; }
    else if (gt < 24) { src = tw1;  dst = pT1;  tile = gt - 16; mode = 0; ncols = 128; }
    else if (gt < 32) { src = pw1;  dst = pP1;  tile = gt - 24; mode = 0; ncols = 128; }
    else if (gt < 56) { src = wih;  dst = pGI;  tile = gt - 32; mode = 1; ncols = 384; }
    else              { src = whh;  dst = pGH;  tile = gt - 56; mode = 1; ncols = 384; }
    int n = tile * 16 + (lane & 15);
    int kbase = kk * 32 + (lane >> 4) * 8;
    unsigned short out[8];
#pragma unroll
    for (int i = 0; i < 8; ++i) {
        int k = kbase + i;
        float v = mode ? src[n * HH + k] : src[k * ncols + n];
        out[i] = f2bf(v);
    }
    *(uint4*)(dst + ((size_t)tile * 256 + kk * 64 + lane) * 8) = *(uint4*)out;
}

// ---------------------------------------------------------------------------
// x time-interleave: xi[n][ci][16] fp32 <- x[t0+ci][n][16]. float4 threads.
__global__ __launch_bounds__(256) void xi_kernel(
    const float* __restrict__ x, float* __restrict__ xi, int t0) {
    int id = blockIdx.x * 256 + threadIdx.x;      // NN*16 float4 slots
    if (id >= NN * 16) return;
    int n = id >> 4, r4 = id & 15;
    int ci = r4 >> 2, f4 = (r4 & 3) * 4;
    float4 v = *(const float4*)(x + ((size_t)(t0 + ci) * NN + n) * IND + f4);
    *(float4*)(xi + (size_t)n * 64 + ci * 16 + f4) = v;
}

// SAGE-1 aggregation over interleaved xi: ONE WAVE PER NODE, all CC
// timesteps at once; 256B contiguous per edge (64 lanes x 4B); 4-edge unroll.
__global__ __launch_bounds__(256) void sage1_agg_kernel(
    const float* __restrict__ xi, const int* __restrict__ offs,
    const int* __restrict__ csr, const float* __restrict__ dinv,
    float* __restrict__ agg1) {
    const int wid = threadIdx.x >> 6, lane = threadIdx.x & 63;
    const int n = blockIdx.x * 4 + wid;
    const int e0 = offs[n], e1 = offs[n + 1];
    float a0 = 0.f, a1 = 0.f, a2 = 0.f, a3 = 0.f;
    int e = e0;
    for (; e + 3 < e1; e += 4) {
        int s0 = csr[e], s1 = csr[e + 1], s2 = csr[e + 2], s3 = csr[e + 3];
        a0 += xi[(size_t)s0 * 64 + lane];
        a1 += xi[(size_t)s1 * 64 + lane];
        a2 += xi[(size_t)s2 * 64 + lane];
        a3 += xi[(size_t)s3 * 64 + lane];
    }
    for (; e < e1; ++e) a0 += xi[(size_t)csr[e] * 64 + lane];
    agg1[(size_t)n * 64 + lane] = (a0 + a1 + a2 + a3) * dinv[n];
}

// SAGE-1 GEMM (gather-free), grid (NN/8, CC): h1 = relu(agg1@wl+bl+x@wr),
// h1c written TIME-INTERLEAVED [n][ci][128].
__global__ __launch_bounds__(128) void sage1_gemm_kernel(
    const float* __restrict__ agg1, const float* __restrict__ xi,
    const float* __restrict__ wl, const float* __restrict__ bl,
    const float* __restrict__ wr, unsigned short* __restrict__ h1c) {
    const int tid = threadIdx.x;
    const int ci = blockIdx.y;
    const int m0 = blockIdx.x * 8;
    __shared__ __align__(16) float sAgg[8][IND];
    __shared__ __align__(16) float sX[8][IND];
    {
        int r = tid >> 4, f = tid & 15;
        sAgg[r][f] = agg1[(size_t)(m0 + r) * 64 + ci * 16 + f];
        sX[r][f]   = xi[(size_t)(m0 + r) * 64 + ci * 16 + f];
    }
    __syncthreads();
    const int col = tid;
    float acc[8];
    float b = bl[col];
#pragma unroll
    for (int m = 0; m < 8; ++m) acc[m] = b;
#pragma unroll
    for (int k = 0; k < IND; ++k) {
        float wlv = wl[k * HH + col];
        float wrv = wr[k * HH + col];
#pragma unroll
        for (int m = 0; m < 8; ++m) acc[m] += sAgg[m][k] * wlv + sX[m][k] * wrv;
    }
#pragma unroll
    for (int m = 0; m < 8; ++m)
        h1c[((size_t)(m0 + m) * CC + ci) * HH + col] = f2bf(fmaxf(acc[m], 0.f));
}

// SAGE-2 aggregation over interleaved h1 (R7 4-deep form — best measured).
#define ADD8(acc, v) do {                                     \
    union { unsigned u; float f; } t_;                        \
    t_.u = (v).x << 16;         acc[0] += t_.f;               \
    t_.u = (v).x & 0xffff0000u; acc[1] += t_.f;               \
    t_.u = (v).y << 16;         acc[2] += t_.f;               \
    t_.u = (v).y & 0xffff0000u; acc[3] += t_.f;               \
    t_.u = (v).z << 16;         acc[4] += t_.f;               \
    t_.u = (v).z & 0xffff0000u; acc[5] += t_.f;               \
    t_.u = (v).w << 16;         acc[6] += t_.f;               \
    t_.u = (v).w & 0xffff0000u; acc[7] += t_.f;               \
} while (0)

__global__ __launch_bounds__(256) void sage2_agg_kernel(
    const unsigned short* __restrict__ h1c, const int* __restrict__ offs,
    const int* __restrict__ csr, const float* __restrict__ dinv,
    unsigned short* __restrict__ agg2c) {
    const int wid = threadIdx.x >> 6, lane = threadIdx.x & 63;
    const int n = blockIdx.x * 4 + wid;
    const char* __restrict__ tb = (const char*)h1c;
    const int lb = lane * 16;
    const int e0 = offs[n], e1 = offs[n + 1];
    float a[8] = {0,0,0,0,0,0,0,0}, b[8] = {0,0,0,0,0,0,0,0};
    float c_[8] = {0,0,0,0,0,0,0,0}, d[8] = {0,0,0,0,0,0,0,0};
    int e = e0;
    for (; e + 3 < e1; e += 4) {
        int s0 = csr[e], s1 = csr[e + 1], s2 = csr[e + 2], s3 = csr[e + 3];
        uint4 v0 = *(const uint4*)(tb + (size_t)s0 * 1024 + lb);
        uint4 v1 = *(const uint4*)(tb + (size_t)s1 * 1024 + lb);
        uint4 v2 = *(const uint4*)(tb + (size_t)s2 * 1024 + lb);
        uint4 v3 = *(const uint4*)(tb + (size_t)s3 * 1024 + lb);
        ADD8(a, v0); ADD8(b, v1); ADD8(c_, v2); ADD8(d, v3);
    }
    for (; e < e1; ++e) {
        int s0 = csr[e];
        uint4 v0 = *(const uint4*)(tb + (size_t)s0 * 1024 + lb);
        ADD8(a, v0);
    }
    float di = dinv[n];
    unsigned short o[8];
#pragma unroll
    for (int j = 0; j < 8; ++j) o[j] = f2bf((a[j] + b[j] + c_[j] + d[j]) * di);
    *(uint4*)((char*)agg2c + (size_t)n * 1024 + lb) = *(uint4*)o;
}

// ---------------------------------------------------------------------------
// A-frag read from XOR-swizzled bf16 LDS tile (16 rows x 128 cols).
#define LDA(buf, kk)                                                          \
    (*(const bf16x8*)((const char*)(buf) +                                    \
        (((lane & 15) * 256 + (kk) * 64 + (lane >> 4) * 16) ^                 \
         (((lane & 15) & 7) << 4))))

// GRU step (R13 structure): sage2-GEMM + LN + GRU. 1 wave, 16 nodes.
// 2 LDS buffers (8KB); __launch_bounds__(64,4) caps VGPR at 128.
__global__ __launch_bounds__(64, 4) void gru_fused_kernel(
    const unsigned short* __restrict__ agg2c, const unsigned short* __restrict__ h1c,
    const unsigned short* __restrict__ pS2L, const unsigned short* __restrict__ pS2R,
    const float* __restrict__ s2bl, const float* __restrict__ lng,
    const float* __restrict__ lnb,
    const unsigned short* __restrict__ pGI, const unsigned short* __restrict__ pGH,
    const float* __restrict__ bih, const float* __restrict__ bhh,
    float* __restrict__ h, unsigned short* __restrict__ hallc, int ci) {
    const int lane = threadIdx.x;
    const int r0 = blockIdx.x * 16;
    __shared__ unsigned short bufA[16 * 128];  // agg2 -> enc
    __shared__ unsigned short bufB[16 * 128];  // h1 -> h_old bf16

#pragma unroll
    for (int j = 0; j < 4; ++j) {
        int off = (lane + 64 * j) * 16;
        int row = off >> 8, colb = off & 255;
        int swz = off ^ ((row & 7) << 4);
        size_t src = (size_t)(r0 + row) * 1024 + (size_t)ci * 256 + colb;
        *(uint4*)((char*)bufA + swz) = *(const uint4*)((const char*)agg2c + src);
        *(uint4*)((char*)bufB + swz) = *(const uint4*)((const char*)h1c + src);
    }
    __syncthreads();

    // register the phase-1 fragments before bufB is recycled
    bf16x8 ae[4], ah[4];
#pragma unroll
    for (int kk = 0; kk < 4; ++kk) { ae[kk] = LDA(bufA, kk); ah[kk] = LDA(bufB, kk); }
    __syncthreads();

    // bufB <- h_old bf16 (loads overlap phase-1 compute below)
#pragma unroll
    for (int j = 0; j < 4; ++j) {
        int off = (lane + 64 * j) * 16;
        int row = off >> 8;
        int swz = off ^ ((row & 7) << 4);
        const float* hs = h + (size_t)r0 * HH + (size_t)(off / 2);
        unsigned short tmp[8];
#pragma unroll
        for (int i = 0; i < 8; ++i) tmp[i] = f2bf(hs[i]);
        *(uint4*)((char*)bufB + swz) = *(uint4*)tmp;
    }

    // ---- phase 1: enc = LN(relu(agg2@wl + bl + h1@wr))
    float vE[8][4];
    float sS[4] = {0, 0, 0, 0}, sQ[4] = {0, 0, 0, 0};
#pragma unroll
    for (int c = 0; c < 8; ++c) {
        f32x4 al = {0, 0, 0, 0}, ar = {0, 0, 0, 0};
#pragma unroll
        for (int kk = 0; kk < 4; ++kk) {
            bf16x8 bl = *(const bf16x8*)(pS2L + ((size_t)(c * 4 + kk) * 64 + lane) * 8);
            bf16x8 br = *(const bf16x8*)(pS2R + ((size_t)(c * 4 + kk) * 64 + lane) * 8);
            al = MFMA(ae[kk], bl, al);
            ar = MFMA(ah[kk], br, ar);
        }
        int col = c * 16 + (lane & 15);
        float bb = s2bl[col];
#pragma unroll
        for (int j = 0; j < 4; ++j) {
            float v = fmaxf(al[j] + ar[j] + bb, 0.f);
            vE[c][j] = v; sS[j] += v; sQ[j] += v * v;
        }
    }
#pragma unroll
    for (int o = 1; o <= 8; o <<= 1) {
#pragma unroll
        for (int j = 0; j < 4; ++j) {
            sS[j] += __shfl_xor(sS[j], o);
            sQ[j] += __shfl_xor(sQ[j], o);
        }
    }
    __syncthreads();
#pragma unroll
    for (int c = 0; c < 8; ++c) {
        int col = c * 16 + (lane & 15);
        float g = lng[col], b = lnb[col];
#pragma unroll
        for (int j = 0; j < 4; ++j) {
            float mu = sS[j] * (1.f / 128.f);
            float var = sQ[j] * (1.f / 128.f) - mu * mu;
            float ve = (vE[c][j] - mu) * rsqrtf(var + 1e-5f) * g + b;
            int row = (lane >> 4) * 4 + j;
            int off = ((row * 128 + col) * 2) ^ ((row & 7) << 4);
            *(unsigned short*)((char*)bufA + off) = f2bf(ve);
        }
    }
    __syncthreads();

    // ---- phase 2: GRU
    bf16x8 xe[4], xh[4];
#pragma unroll
    for (int kk = 0; kk < 4; ++kk) { xe[kk] = LDA(bufA, kk); xh[kk] = LDA(bufB, kk); }
#pragma unroll
    for (int c = 0; c < 8; ++c) {
        f32x4 air = {0,0,0,0}, aiz = {0,0,0,0}, ain = {0,0,0,0};
        f32x4 ahr = {0,0,0,0}, ahz = {0,0,0,0}, ahn = {0,0,0,0};
#pragma unroll
        for (int kk = 0; kk < 4; ++kk) {
            bf16x8 bir = *(const bf16x8*)(pGI + ((size_t)((c     ) * 4 + kk) * 64 + lane) * 8);
            bf16x8 biz = *(const bf16x8*)(pGI + ((size_t)((c +  8) * 4 + kk) * 64 + lane) * 8);
            bf16x8 bin = *(const bf16x8*)(pGI + ((size_t)((c + 16) * 4 + kk) * 64 + lane) * 8);
            bf16x8 bhr = *(const bf16x8*)(pGH + ((size_t)((c     ) * 4 + kk) * 64 + lane) * 8);
            bf16x8 bhz = *(const bf16x8*)(pGH + ((size_t)((c +  8) * 4 + kk) * 64 + lane) * 8);
            bf16x8 bhn = *(const bf16x8*)(pGH + ((size_t)((c + 16) * 4 + kk) * 64 + lane) * 8);
            air = MFMA(xe[kk], bir, air); aiz = MFMA(xe[kk], biz, aiz);
            ain = MFMA(xe[kk], bin, ain);
            ahr = MFMA(xh[kk], bhr, ahr); ahz = MFMA(xh[kk], bhz, ahz);
            ahn = MFMA(xh[kk], bhn, ahn);
        }
        int col = c * 16 + (lane & 15);
        float bir_ = bih[col], biz_ = bih[HH + col], bin_ = bih[2 * HH + col];
        float bhr_ = bhh[col], bhz_ = bhh[HH + col], bhn_ = bhh[2 * HH + col];
#pragma unroll
        for (int j = 0; j < 4; ++j) {
            int row = (lane >> 4) * 4 + j;
            size_t gidx = (size_t)(r0 + row) * HH + col;
            float rr = 1.f / (1.f + expf(-(air[j] + bir_ + ahr[j] + bhr_)));
            float zz = 1.f / (1.f + expf(-(aiz[j] + biz_ + ahz[j] + bhz_)));
            float nn2 = tanhf(ain[j] + bin_ + rr * (ahn[j] + bhn_));
            float hold = h[gidx];
            float hnew = (1.f - zz) * nn2 + zz * hold;
            h[gidx] = hnew;
            hallc[((size_t)(r0 + row) * CC + ci) * HH + col] = f2bf(hnew);
        }
    }
}

// Decoders (R13 structure), one launch per chunk over all CC slices.
__global__ __launch_bounds__(64) void dec_kernel(
    const unsigned short* __restrict__ hall,
    const unsigned short* __restrict__ pT1, const unsigned short* __restrict__ pP1,
    const float* __restrict__ tb1, const float* __restrict__ tw2,
    const float* __restrict__ tb2, const float* __restrict__ pb1,
    const float* __restrict__ pw2, const float* __restrict__ pb2,
    float* __restrict__ out_th, float* __restrict__ out_ph, int t0) {
    const int lane = threadIdx.x;
    const int rc = blockIdx.x * 16;          // row within chunk (ci-major)
    const int ci = rc / NN;
    const int n0 = rc - ci * NN;             // NN % 16 == 0 -> no straddle
    const int tg = t0 + ci;
    __shared__ unsigned short bufB[16 * 128];
#pragma unroll
    for (int j = 0; j < 4; ++j) {
        int off = (lane + 64 * j) * 16;
        int row = off >> 8, colb = off & 255;
        int swz = off ^ ((row & 7) << 4);
        *(uint4*)((char*)bufB + swz) =
            *(const uint4*)((const char*)hall +
                            (size_t)(n0 + row) * 1024 + (size_t)ci * 256 + colb);
    }
    __syncthreads();
    bf16x8 xd[4];
#pragma unroll
    for (int kk = 0; kk < 4; ++kk) xd[kk] = LDA(bufB, kk);
    float pt[4] = {0, 0, 0, 0};
    float pf[NPF][4];
#pragma unroll
    for (int f = 0; f < NPF; ++f)
#pragma unroll
        for (int j = 0; j < 4; ++j) pf[f][j] = 0.f;
#pragma unroll
    for (int c = 0; c < 8; ++c) {
        f32x4 at = {0, 0, 0, 0}, ap = {0, 0, 0, 0};
#pragma unroll
        for (int kk = 0; kk < 4; ++kk) {
            bf16x8 bt = *(const bf16x8*)(pT1 + ((size_t)(c * 4 + kk) * 64 + lane) * 8);
            bf16x8 bp = *(const bf16x8*)(pP1 + ((size_t)(c * 4 + kk) * 64 + lane) * 8);
            at = MFMA(xd[kk], bt, at);
            ap = MFMA(xd[kk], bp, ap);
        }
        int col = c * 16 + (lane & 15);
        float b1 = tb1[col], b2 = pb1[col], w2 = tw2[col];
        float wp[NPF];
#pragma unroll
        for (int f = 0; f < NPF; ++f) wp[f] = pw2[col * NPF + f];
#pragma unroll
        for (int j = 0; j < 4; ++j) {
            float a = fmaxf(at[j] + b1, 0.f);
            pt[j] += a * w2;
            float p = fmaxf(ap[j] + b2, 0.f);
#pragma unroll
            for (int f = 0; f < NPF; ++f) pf[f][j] += p * wp[f];
        }
    }
#pragma unroll
    for (int o = 1; o <= 8; o <<= 1) {
#pragma unroll
        for (int j = 0; j < 4; ++j) {
            pt[j] += __shfl_xor(pt[j], o);
#pragma unroll
            for (int f = 0; f < NPF; ++f) pf[f][j] += __shfl_xor(pf[f][j], o);
        }
    }
    if ((lane & 15) == 0) {
        int g = lane >> 4;
#pragma unroll
        for (int j = 0; j < 4; ++j) {
            int gr = n0 + g * 4 + j;
            out_th[(size_t)tg * NN + gr] = pt[j] + tb2[0];
#pragma unroll
            for (int f = 0; f < NPF; ++f)
                out_ph[((size_t)tg * NN + gr) * NPF + f] = pf[f][j] + pb2[f];
        }
    }
}
#undef LDA

// ---------------------------------------------------------------------------
extern "C" void kernel_launch(void* const* d_in, const int* in_sizes, int n_in,
                              void* d_out, int out_size, void* d_ws, size_t ws_size,
                              hipStream_t stream) {
    const float* x     = (const float*)d_in[0];
    const int*   ei    = (const int*)d_in[1];
    const float* s1wl  = (const float*)d_in[2];
    const float* s1bl  = (const float*)d_in[3];
    const float* s1wr  = (const float*)d_in[4];
    const float* s2wl  = (const float*)d_in[5];
    const float* s2bl  = (const float*)d_in[6];
    const float* s2wr  = (const float*)d_in[7];
    const float* lng   = (const float*)d_in[8];
    const float* lnb   = (const float*)d_in[9];
    const float* g_wih = (const float*)d_in[10];
    const float* g_whh = (const float*)d_in[11];
    const float* g_bih = (const float*)d_in[12];
    const float* g_bhh = (const float*)d_in[13];
    const float* tw1   = (const float*)d_in[14];
    const float* tb1   = (const float*)d_in[15];
    const float* tw2   = (const float*)d_in[16];
    const float* tb2   = (const float*)d_in[17];
    const float* pw1   = (const float*)d_in[18];
    const float* pb1   = (const float*)d_in[19];
    const float* pw2   = (const float*)d_in[20];
    const float* pb2   = (const float*)d_in[21];

    char* ws = (char*)d_ws;
    size_t o = 0;
    auto alloc = [&](size_t bytes) {
        size_t r = o;
        o += (bytes + 255) & ~(size_t)255;
        return r;
    };
    int*            flag  = (int*)(ws + alloc(4));
    int*            deg   = (int*)(ws + alloc((size_t)NN * 4));
    int*            offs  = (int*)(ws + alloc((size_t)(NN + 1) * 4));
    int*            curs  = (int*)(ws + alloc((size_t)NN * 4));
    int*            csr   = (int*)(ws + alloc((size_t)EE * 4));
    float*          dinv  = (float*)(ws + alloc((size_t)NN * 4));
    int*            bsum  = (int*)(ws + alloc((size_t)NB * 4));
    int*            bbase = (int*)(ws + alloc((size_t)NB * 4));
    unsigned short* pS2L  = (unsigned short*)(ws + alloc(8 * 4 * 64 * 8 * 2));
    unsigned short* pS2R  = (unsigned short*)(ws + alloc(8 * 4 * 64 * 8 * 2));
    unsigned short* pT1   = (unsigned short*)(ws + alloc(8 * 4 * 64 * 8 * 2));
    unsigned short* pP1   = (unsigned short*)(ws + alloc(8 * 4 * 64 * 8 * 2));
    unsigned short* pGI   = (unsigned short*)(ws + alloc(24 * 4 * 64 * 8 * 2));
    unsigned short* pGH   = (unsigned short*)(ws + alloc(24 * 4 * 64 * 8 * 2));
    float*          hbuf  = (float*)(ws + alloc((size_t)NN * HH * 4));
    unsigned short* h1c   = (unsigned short*)(ws + alloc((size_t)NN * CC * HH * 2));
    unsigned short* agg2c = (unsigned short*)(ws + alloc((size_t)NN * CC * HH * 2));
    unsigned short* hallc = agg2c;  // alias: gru writes hall over consumed agg2
    // xi/agg1 alias the agg2c region (dead before sage2_agg writes it):
    float*          xi    = (float*)agg2c;                   // 12.8 MB
    float*          agg1  = (float*)((char*)agg2c + (size_t)NN * 64 * 4);  // 12.8 MB

    // Prep (identical every call).
    detect_kernel<<<1, 256, 0, stream>>>(ei, flag, EE);
    hipMemsetAsync(deg, 0, (size_t)NN * 4, stream);
    count_deg_kernel<<<(EE + 255) / 256, 256, 0, stream>>>(ei, flag, deg, EE);
    sum_blocks_kernel<<<NB, 256, 0, stream>>>(deg, bsum);
    scan_blocks_kernel<<<1, 256, 0, stream>>>(bsum, bbase);
    offs_kernel<<<NB, 256, 0, stream>>>(deg, bbase, offs, curs, dinv, EE);
    fill_csr_kernel<<<(EE + 255) / 256, 256, 0, stream>>>(ei, flag, curs, csr, EE);
    pack_all_kernel<<<(80 * 256 + 255) / 256, 256, 0, stream>>>(
        s2wl, s2wr, tw1, pw1, g_wih, g_whh, pS2L, pS2R, pT1, pP1, pGI, pGH);
    hipMemsetAsync(hbuf, 0, (size_t)NN * HH * 4, stream);

    float* out = (float*)d_out;
    for (int t0 = 0; t0 < TT; t0 += CC) {
        dim3 gg(NN / 8, CC);
        xi_kernel<<<(NN * 16 + 255) / 256, 256, 0, stream>>>(x, xi, t0);
        sage1_agg_kernel<<<NN / 4, 256, 0, stream>>>(xi, offs, csr, dinv, agg1);
        sage1_gemm_kernel<<<gg, 128, 0, stream>>>(agg1, xi, s1wl, s1bl, s1wr, h1c);
        sage2_agg_kernel<<<NN / 4, 256, 0, stream>>>(h1c, offs, csr, dinv, agg2c);
        for (int ci = 0; ci < CC; ++ci) {
            gru_fused_kernel<<<NN / 16, 64, 0, stream>>>(
                agg2c, h1c, pS2L, pS2R, s2bl, lng, lnb, pGI, pGH,
                g_bih, g_bhh, hbuf, hallc, ci);
        }
        dec_kernel<<<CC * NN / 16, 64, 0, stream>>>(
            hallc, pT1, pP1, tb1, tw2, tb2, pb1, pw2, pb2,
            out, out + (size_t)TT * NN, t0);
    }
}